// Round 5
// baseline (160.877 us; speedup 1.0000x reference)
//
#include <hip/hip_runtime.h>

// MultiScaleSampler R12: block-level counting sort kills the random-sector tax.
// Measured: ~6 points share each 32B output sector but arrive from different
// XCDs/times -> zero L2 merging -> 50-64MB of sector writes at ~1.1TB/s in
// every prior variant. Fix: Pass A bins points by pixel row (bucket=yi>>11,
// span 2048 = image row) via LDS histogram + one global atomic per
// (block,bucket); records of a bucket land in consecutive slots from one CU
// -> L2 merges. Pass B: one block per row-bucket runs the verified MFMA MLP
// on its compact records, scatters 3xf16 results into an LDS row tile, and
// flushes the row densely (25.2MB written exactly once, full lines).
// No sentinel memset, no expand pass, no global scatter.
// MFMA core (fragments, wave-private LDS layout, LAYER macro, layer-4 stash,
// softmax) verbatim from the harness-verified R7/R11 kernel.

#define W_IMG 2048
#define NF    32
#define SPAN  2048     // bucket span in pixels == W_IMG, so py == bucket
#define MAXK  2048     // LDS histogram capacity (K = HW/SPAN = 1024 here)

typedef __attribute__((ext_vector_type(8))) _Float16 f16x8;
typedef __attribute__((ext_vector_type(4))) _Float16 f16x4;
typedef __attribute__((ext_vector_type(4))) float    f32x4;

static __device__ __forceinline__ unsigned packfeat(float fx, float fy) {
    unsigned short ux = __builtin_bit_cast(unsigned short, (_Float16)fx);
    unsigned short uy = __builtin_bit_cast(unsigned short, (_Float16)fy);
    return ((unsigned)uy << 16) | (unsigned)ux;
}

// ---- Pass A: block-level counting sort of points into row buckets ----
__global__ __launch_bounds__(512) void bin_points(
    const float* __restrict__ grid, const int* __restrict__ yi,
    uint2* __restrict__ recs, unsigned* __restrict__ gcnt,
    int N, int K, int CAP, int PPB)
{
    __shared__ unsigned lcnt[MAXK];
    __shared__ unsigned lbase[MAXK];
    const int tid  = threadIdx.x;
    const int base = blockIdx.x * PPB;
    const int cnt  = min(PPB, N - base);

    for (int b = tid; b < K; b += 512) lcnt[b] = 0;
    __syncthreads();

    // phase 1: local histogram
    for (int j = tid; j < cnt; j += 512) {
        unsigned b = ((unsigned)yi[base + j]) >> 11;
        atomicAdd(&lcnt[b], 1u);
    }
    __syncthreads();

    // phase 2: reserve contiguous global ranges per bucket
    for (int b = tid; b < K; b += 512) {
        unsigned c = lcnt[b];
        lbase[b] = c ? atomicAdd(&gcnt[b], c) : 0u;
        lcnt[b]  = 0;
    }
    __syncthreads();

    // phase 3: scatter records into reserved (consecutive!) slots
    for (int j = tid; j < cnt; j += 512) {
        int i = base + j;
        unsigned y   = (unsigned)yi[i];
        unsigned b   = y >> 11;
        unsigned loc = y & 2047u;
        float gx = grid[i], gy = grid[N + i];
        float fx = gx - floorf(gx), fy = gy - floorf(gy);
        unsigned pos = lbase[b] + atomicAdd(&lcnt[b], 1u);
        if (pos < (unsigned)CAP) {
            uint2 r; r.x = packfeat(fx, fy); r.y = loc;
            recs[(size_t)b * CAP + pos] = r;
        }
    }
}

// ---- Pass B: per-row-bucket MFMA MLP + LDS tile + dense flush ----
__global__ __launch_bounds__(256, 4) void mlp_tiles(
    const float* __restrict__ m,          // (3,3)
    const float* __restrict__ W1, const float* __restrict__ b1,   // (5,32),(32)
    const float* __restrict__ W2, const float* __restrict__ b2,   // (32,32),(32)
    const float* __restrict__ W3, const float* __restrict__ b3,   // (32,32),(32)
    const float* __restrict__ W4, const float* __restrict__ b4,   // (32,3),(3)
    const uint2* __restrict__ recs, const unsigned* __restrict__ gcnt,
    float* __restrict__ out, int HW, int CAP)
{
    const int tid  = threadIdx.x;
    const int lane = tid & 63;
    const int wave = tid >> 6;
    const int lm   = lane & 15;
    const int lq   = lane >> 4;
    const int bkt  = blockIdx.x;

    __shared__ __align__(16) char smem[4 * 8192];
    __shared__ unsigned long long tile[SPAN + 1];   // 3xf16 per px; [SPAN]=dummy
    char* buf = smem + wave * 8192;   // 8 tiles x 1024B, wave-private

    // zero the row tile
    for (int p = tid; p < SPAN + 1; p += 256) tile[p] = 0ull;

    // ---- one-time weight fragments (A = W^T: A[m=out][k=in]) ----
    f16x8 a1[2], a2[2], a3[2], a4;
    f32x4 cb1[2], cb2[2], cb3[2], cb4;
#pragma unroll
    for (int mh = 0; mh < 2; ++mh) {
        int outc = 16 * mh + lm;
#pragma unroll
        for (int j = 0; j < 8; ++j) {
            int k = lq * 8 + j;
            a1[mh][j] = (k < 5) ? (_Float16)W1[k * NF + outc] : (_Float16)0.0f;
            a2[mh][j] = (_Float16)W2[k * NF + outc];
            a3[mh][j] = (_Float16)W3[k * NF + outc];
        }
#pragma unroll
        for (int r = 0; r < 4; ++r) {
            int o = 16 * mh + lq * 4 + r;
            cb1[mh][r] = b1[o];
            cb2[mh][r] = b2[o];
            cb3[mh][r] = b3[o];
        }
    }
#pragma unroll
    for (int j = 0; j < 8; ++j) {
        int k = lq * 8 + j;
        a4[j] = (lm < 3) ? (_Float16)W4[k * 3 + lm] : (_Float16)0.0f;
    }
#pragma unroll
    for (int r = 0; r < 4; ++r) {
        int o = lq * 4 + r;
        cb4[r] = (o < 3) ? b4[o] : 0.f;
    }

    // ---- uniform homography scalars (py == bkt for the whole block) ----
    float m00=m[0], m01=m[1], m02=m[2];
    float m10=m[3], m11=m[4], m12=m[5];
    float m20=m[6], m21=m[7], m22=m[8];
    float det = m00*(m11*m22 - m12*m21)
              - m01*(m10*m22 - m12*m20)
              + m02*(m10*m21 - m11*m20);
    float adet = fabsf(det);
    float rowt = m21 * (float)bkt + m22;

    // write offset for D-frag (mh, tile T): consumer lane (2mh + lq/2, lm),
    // half (lq&1)
    const int woff = ((lq >> 1) * 16 + lm) * 16 + (lq & 1) * 8;

    int cnt = (int)gcnt[bkt];
    if (cnt > CAP) cnt = CAP;
    const uint2* br = recs + (size_t)bkt * CAP;

    __syncthreads();   // tile zeroed before any scatter

    const int ngrp = (cnt + 511) >> 9;
#pragma unroll 1
    for (int g = 0; g < ngrp; ++g) {
        const int q0 = g * 512 + wave * 128;
        unsigned loc2[2];

        // ---- features for 2 points/lane from records; write B-frag slot ----
#pragma unroll
        for (int t = 0; t < 2; ++t) {
            int idx = q0 + t * 64 + lane;
            uint2 r;
            if (idx < cnt) r = br[idx];
            else { r.x = 0u; r.y = (unsigned)SPAN; }   // dummy -> tile[SPAN]
            loc2[t] = r.y;
            float px    = (float)(r.y < (unsigned)SPAN ? r.y : 0u);
            float denom = m20 * px + rowt;
            float ad    = fabsf(denom);
            float dsda  = fminf(adet * __builtin_amdgcn_rcpf(ad*ad*ad), 60000.f);
            _Float16 hx = __builtin_bit_cast(_Float16, (unsigned short)(r.x & 0xFFFFu));
            _Float16 hy = __builtin_bit_cast(_Float16, (unsigned short)(r.x >> 16));
            float fxf = (float)hx, fyf = (float)hy;
            f16x8 f;
            f[0] = hx;                   f[1] = hy;
            f[2] = (_Float16)(1.f-fxf);  f[3] = (_Float16)(1.f-fyf);
            f[4] = (_Float16)dsda;       f[5] = (_Float16)0.0f;
            f[6] = (_Float16)0.0f;       f[7] = (_Float16)0.0f;
            int tb = t * 4 + lq;         // tile-buf of this point
            *(f16x8*)(buf + tb * 1024 + lm * 16) = f;  // consumer slot (lq_c=0,lm)
        }
        // zero k=8..31 regions of all 8 tiles (48 chunks x 16B per tile)
        {
            f16x8 z = {};
#pragma unroll
            for (int j = 0; j < 6; ++j) {
                int T  = lane >> 3;
                int ch = (lane & 7) + 8 * j;
                *(f16x8*)(buf + T * 1024 + 256 + ch * 16) = z;
            }
        }

        // ---- layers 1..3: read B-frags, MFMA, relu+clamp+cvt, write frags ----
#define LAYER(AF, CB)                                                          \
        _Pragma("unroll")                                                      \
        for (int tg = 0; tg < 2; ++tg) {                                       \
            f16x8 bf[4];                                                       \
            _Pragma("unroll")                                                  \
            for (int q = 0; q < 4; ++q)                                        \
                bf[q] = *(const f16x8*)(buf + (tg*4 + q) * 1024 + lane * 16);  \
            _Pragma("unroll")                                                  \
            for (int q = 0; q < 4; ++q) {                                      \
                int T = tg * 4 + q;                                            \
                _Pragma("unroll")                                              \
                for (int mh = 0; mh < 2; ++mh) {                               \
                    f32x4 d = __builtin_amdgcn_mfma_f32_16x16x32_f16(          \
                        AF[mh], bf[q], CB[mh], 0, 0, 0);                       \
                    f16x4 o;                                                   \
                    _Pragma("unroll")                                          \
                    for (int r = 0; r < 4; ++r)                                \
                        o[r] = (_Float16)fminf(fmaxf(d[r], 0.f), 60000.f);     \
                    *(f16x4*)(buf + T * 1024 + mh * 512 + woff) = o;           \
                }                                                              \
            }                                                                  \
        }

        LAYER(a1, cb1)
        LAYER(a2, cb2)
        LAYER(a3, cb3)
#undef LAYER

        // ---- layer 4: one MFMA per tile; logits (rows 0..2) in lq==0 lanes;
        //      stash to pt-indexed slots (first 2KB, tiles consumed) ----
#pragma unroll
        for (int tg = 0; tg < 2; ++tg) {
            f16x8 bf[4];
#pragma unroll
            for (int q = 0; q < 4; ++q)
                bf[q] = *(const f16x8*)(buf + (tg*4 + q) * 1024 + lane * 16);
#pragma unroll
            for (int q = 0; q < 4; ++q) {
                int T = tg * 4 + q;
                f32x4 d = __builtin_amdgcn_mfma_f32_16x16x32_f16(a4, bf[q], cb4, 0, 0, 0);
                if (lq == 0)
                    *(f32x4*)(buf + (T * 16 + lm) * 16) = d;   // pt slot, 16B
            }
        }

        // ---- softmax -> 3xf16 into the LDS row tile ----
#pragma unroll
        for (int t = 0; t < 2; ++t) {
            int s = t * 64 + lane;
            f32x4 L = *(const f32x4*)(buf + s * 16);
            float l0 = L[0], l1 = L[1], l2 = L[2];
            float mx = fmaxf(l0, fmaxf(l1, l2));
            float e0 = __expf(l0 - mx), e1 = __expf(l1 - mx), e2 = __expf(l2 - mx);
            float inv = __builtin_amdgcn_rcpf(e0 + e1 + e2);
            unsigned long long u0 =
                __builtin_bit_cast(unsigned short, (_Float16)(e0 * inv));
            unsigned long long u1 =
                __builtin_bit_cast(unsigned short, (_Float16)(e1 * inv));
            unsigned long long u2 =
                __builtin_bit_cast(unsigned short, (_Float16)(e2 * inv));
            tile[loc2[t]] = u0 | (u1 << 16) | (u2 << 32);
        }
    }

    __syncthreads();   // all scatters into tile complete

    // ---- dense flush: whole row, fully coalesced (96B per thread) ----
    {
        int limit = min(SPAN, HW - bkt * SPAN);
        int p0 = tid * 8;
        if (p0 + 8 <= limit) {
            float w[24];
#pragma unroll
            for (int k = 0; k < 8; ++k) {
                unsigned long long v = tile[p0 + k];
                w[3*k + 0] = (float)__builtin_bit_cast(_Float16, (unsigned short)(v       & 0xFFFFu));
                w[3*k + 1] = (float)__builtin_bit_cast(_Float16, (unsigned short)((v>>16) & 0xFFFFu));
                w[3*k + 2] = (float)__builtin_bit_cast(_Float16, (unsigned short)((v>>32) & 0xFFFFu));
            }
            float4* o = (float4*)(out + (size_t)bkt * SPAN * 3 + (size_t)p0 * 3);
#pragma unroll
            for (int k = 0; k < 6; ++k)
                o[k] = make_float4(w[4*k], w[4*k+1], w[4*k+2], w[4*k+3]);
        } else {
            for (int p = p0; p < limit; ++p) {
                unsigned long long v = tile[p];
                float* o = out + ((size_t)bkt * SPAN + p) * 3;
                o[0] = (float)__builtin_bit_cast(_Float16, (unsigned short)(v       & 0xFFFFu));
                o[1] = (float)__builtin_bit_cast(_Float16, (unsigned short)((v>>16) & 0xFFFFu));
                o[2] = (float)__builtin_bit_cast(_Float16, (unsigned short)((v>>32) & 0xFFFFu));
            }
        }
    }
}

extern "C" void kernel_launch(void* const* d_in, const int* in_sizes, int n_in,
                              void* d_out, int out_size, void* d_ws, size_t ws_size,
                              hipStream_t stream) {
    const float* grid = (const float*)d_in[0];
    const int*   yi   = (const int*)  d_in[1];
    const float* m    = (const float*)d_in[2];
    const float* W1   = (const float*)d_in[3];
    const float* b1   = (const float*)d_in[4];
    const float* W2   = (const float*)d_in[5];
    const float* b2   = (const float*)d_in[6];
    const float* W3   = (const float*)d_in[7];
    const float* b3   = (const float*)d_in[8];
    const float* W4   = (const float*)d_in[9];
    const float* b4   = (const float*)d_in[10];
    float* out = (float*)d_out;

    int N  = in_sizes[1];      // number of sampled points
    int HW = out_size / 3;     // number of output pixels

    int K   = (HW + SPAN - 1) / SPAN;   // 1024 row buckets (K <= MAXK assumed)
    int avg = (N + K - 1) / K;
    int CAP = avg + avg / 2 + 64;       // 1.5x mean + slack; overflow P ~ 0
    // workspace layout: [0,16K) gcnt, [16K, ...) records
    if (16384 + (size_t)K * CAP * 8 > ws_size)
        CAP = (int)((ws_size - 16384) / (8 * (size_t)K));
    unsigned* gcnt = (unsigned*)d_ws;
    uint2*    recs = (uint2*)((char*)d_ws + 16384);

    hipMemsetAsync(gcnt, 0, (size_t)K * sizeof(unsigned), stream);

    const int PPB = 8192;
    int ablocks = (N + PPB - 1) / PPB;
    bin_points<<<ablocks, 512, 0, stream>>>(grid, yi, recs, gcnt, N, K, CAP, PPB);

    mlp_tiles<<<K, 256, 0, stream>>>(
        m, W1, b1, W2, b2, W3, b3, W4, b4, recs, gcnt, out, HW, CAP);
}